// Round 1
// baseline (4124.363 us; speedup 1.0000x reference)
//
#include <hip/hip_runtime.h>
#include <math.h>

#define CDIM 256
#define NSEQ 4096
#define HWDIM 64

// ---------------------------------------------------------------------------
// conv3x3 (SAME, stride 1, no bias) + ReLU, output stored TRANSPOSED: yT[b][n][co]
// block: 256 threads = 16x16 spatial tile; 8 output channels per block
// grid: (16 tiles, 32 co-groups, 4 batch)
// ---------------------------------------------------------------------------
__global__ __launch_bounds__(256)
void conv3x3_relu_T_kernel(const float* __restrict__ x, const float* __restrict__ w,
                           float* __restrict__ yT)
{
    __shared__ float tile[4 * 18 * 18];   // 4 input channels x 18x18 halo tile
    const int tid = threadIdx.x;
    const int tx = tid & 15, ty = tid >> 4;
    const int tb = blockIdx.x;                  // 0..15
    const int y0 = (tb >> 2) << 4;
    const int x0 = (tb & 3) << 4;
    const int cob = blockIdx.y << 3;            // 8 output channels
    const int b = blockIdx.z;

    float acc[8] = {0.f,0.f,0.f,0.f,0.f,0.f,0.f,0.f};

    for (int cib = 0; cib < CDIM; cib += 4) {
        __syncthreads();   // previous compute done before restaging
        #pragma unroll
        for (int k = 0; k < 6; ++k) {
            int e = tid + (k << 8);
            if (e < 1296) {
                int cc = e / 324;
                int rem = e - cc * 324;
                int r = rem / 18;
                int cl = rem - r * 18;
                int gy = y0 + r - 1, gx = x0 + cl - 1;
                float v = 0.0f;
                if (gy >= 0 && gy < HWDIM && gx >= 0 && gx < HWDIM)
                    v = x[(((size_t)b * CDIM + (cib + cc)) * HWDIM + gy) * HWDIM + gx];
                tile[e] = v;
            }
        }
        __syncthreads();
        #pragma unroll
        for (int cc = 0; cc < 4; ++cc) {
            float xr[9];
            #pragma unroll
            for (int dy = 0; dy < 3; ++dy)
                #pragma unroll
                for (int dx = 0; dx < 3; ++dx)
                    xr[dy * 3 + dx] = tile[cc * 324 + (ty + dy) * 18 + (tx + dx)];
            #pragma unroll
            for (int co = 0; co < 8; ++co) {
                // block-uniform address -> scalar loads through K$
                const float* __restrict__ wp = &w[((size_t)(cob + co) * CDIM + (cib + cc)) * 9];
                acc[co] += xr[0]*wp[0] + xr[1]*wp[1] + xr[2]*wp[2]
                         + xr[3]*wp[3] + xr[4]*wp[4] + xr[5]*wp[5]
                         + xr[6]*wp[6] + xr[7]*wp[7] + xr[8]*wp[8];
            }
        }
    }

    const int n = (y0 + ty) * HWDIM + x0 + tx;
    float4 o0, o1;
    o0.x = fmaxf(acc[0], 0.f); o0.y = fmaxf(acc[1], 0.f);
    o0.z = fmaxf(acc[2], 0.f); o0.w = fmaxf(acc[3], 0.f);
    o1.x = fmaxf(acc[4], 0.f); o1.y = fmaxf(acc[5], 0.f);
    o1.z = fmaxf(acc[6], 0.f); o1.w = fmaxf(acc[7], 0.f);
    float* yp = &yT[((size_t)b * NSEQ + n) * CDIM + cob];
    *(float4*)yp = o0;
    *(float4*)(yp + 4) = o1;
}

// ---------------------------------------------------------------------------
// Flash self-attention (Q=K=XT, V=VT), softmax over keys n (valid because the
// score Gram matrix is symmetric => axis-1 softmax == row softmax).
// out[b,c,m] = gamma * (sum_n p_mn * VT[b,n,c]) + ref[b,c,m]
// block: 256 threads (4 waves); 16 queries/block; n processed in chunks of 64.
// ---------------------------------------------------------------------------
#define M_TILE 16
#define N_CHUNK 64
#define KT_STR 65     // [CDIM][N_CHUNK+1]  (odd stride -> conflict-free column reads)
#define V_STR  260    // [N_CHUNK][CDIM+4]  (16B-aligned rows for b128 reads)
#define P_STR  65

__global__ __launch_bounds__(256)
void attn_kernel(const float* __restrict__ XT, const float* __restrict__ VT,
                 const float* __restrict__ ref, const float* __restrict__ gptr,
                 float* __restrict__ out)
{
    __shared__ float Q_lds[M_TILE * CDIM];      // 16 KB
    __shared__ float KT_lds[CDIM * KT_STR];     // 66.6 KB (K transposed: [c][n])
    __shared__ float V_lds[N_CHUNK * V_STR];    // 66.6 KB ([n][c])
    __shared__ float P_lds[M_TILE * P_STR];     // 4.2 KB

    const int tid = threadIdx.x;
    const int lane = tid & 63;
    const int wv = tid >> 6;          // wave 0..3, owns queries wv*4 .. wv*4+3
    const int b = blockIdx.y;
    const int m0 = blockIdx.x * M_TILE;

    const float4* XT4 = (const float4*)XT;
    const float4* VT4 = (const float4*)VT;

    // stage Q tile: 16 rows x 256
    #pragma unroll
    for (int i = 0; i < 4; ++i) {
        int f = tid + (i << 8);
        int r = f >> 6, c4 = f & 63;
        float4 qv = XT4[(size_t)(b * NSEQ + m0 + r) * (CDIM / 4) + c4];
        *(float4*)&Q_lds[r * CDIM + (c4 << 2)] = qv;
    }

    float m_run[4], l_run[4], accv[4][4];
    #pragma unroll
    for (int q = 0; q < 4; ++q) {
        m_run[q] = -INFINITY; l_run[q] = 0.f;
        accv[q][0] = accv[q][1] = accv[q][2] = accv[q][3] = 0.f;
    }

    for (int n0 = 0; n0 < NSEQ; n0 += N_CHUNK) {
        __syncthreads();   // previous PV readers done (also orders Q staging on iter 0)
        // stage K (transposed) + V rows n0..n0+63
        #pragma unroll
        for (int i = 0; i < 16; ++i) {
            int f = tid + (i << 8);
            int r = f >> 6, c4 = f & 63;
            size_t g = (size_t)(b * NSEQ + n0 + r) * (CDIM / 4) + c4;
            float4 kv = XT4[g];
            int c = c4 << 2;
            KT_lds[(c + 0) * KT_STR + r] = kv.x;
            KT_lds[(c + 1) * KT_STR + r] = kv.y;
            KT_lds[(c + 2) * KT_STR + r] = kv.z;
            KT_lds[(c + 3) * KT_STR + r] = kv.w;
            float4 vv = VT4[g];
            *(float4*)&V_lds[r * V_STR + c] = vv;
        }
        __syncthreads();

        // QK^T: lane owns key n = n0+lane; computes scores for this wave's 4 queries
        float s[4] = {0.f, 0.f, 0.f, 0.f};
        const float* qbase = &Q_lds[(wv << 2) * CDIM];
        #pragma unroll 4
        for (int c = 0; c < CDIM; ++c) {
            float kc = KT_lds[c * KT_STR + lane];
            s[0] += qbase[c] * kc;
            s[1] += qbase[CDIM + c] * kc;
            s[2] += qbase[2 * CDIM + c] * kc;
            s[3] += qbase[3 * CDIM + c] * kc;
        }

        // online softmax (per query, 64-lane butterfly reductions)
        #pragma unroll
        for (int q = 0; q < 4; ++q) {
            float cmax = s[q];
            #pragma unroll
            for (int off = 32; off > 0; off >>= 1)
                cmax = fmaxf(cmax, __shfl_xor(cmax, off, 64));
            float mnew = fmaxf(m_run[q], cmax);
            float p = __expf(s[q] - mnew);
            float csum = p;
            #pragma unroll
            for (int off = 32; off > 0; off >>= 1)
                csum += __shfl_xor(csum, off, 64);
            float alpha = __expf(m_run[q] - mnew);
            m_run[q] = mnew;
            l_run[q] = l_run[q] * alpha + csum;
            P_lds[((wv << 2) + q) * P_STR + lane] = p;
            accv[q][0] *= alpha; accv[q][1] *= alpha;
            accv[q][2] *= alpha; accv[q][3] *= alpha;
        }

        // PV: wave-local LDS RAW on P_lds (same-wave DS ops are in-order).
        // lane owns channels c = lane*4 .. +3
        #pragma unroll 4
        for (int n = 0; n < N_CHUNK; ++n) {
            float4 vv = *(const float4*)&V_lds[n * V_STR + (lane << 2)];
            #pragma unroll
            for (int q = 0; q < 4; ++q) {
                float p = P_lds[((wv << 2) + q) * P_STR + n];
                accv[q][0] += p * vv.x;
                accv[q][1] += p * vv.y;
                accv[q][2] += p * vv.z;
                accv[q][3] += p * vv.w;
            }
        }
    }

    __syncthreads();
    // normalize; park A[m][c] in (reused) KT_lds for a coalesced transpose-out
    #pragma unroll
    for (int q = 0; q < 4; ++q) {
        float inv = 1.0f / l_run[q];
        float4 a;
        a.x = accv[q][0] * inv; a.y = accv[q][1] * inv;
        a.z = accv[q][2] * inv; a.w = accv[q][3] * inv;
        *(float4*)&KT_lds[((wv << 2) + q) * V_STR + (lane << 2)] = a;
    }
    __syncthreads();

    const float g = gptr[0];
    // out layout [b][c][m]: 16 consecutive m per thread-group -> 64B coalesced
    #pragma unroll
    for (int i = 0; i < 16; ++i) {
        int f = tid + (i << 8);
        int c = f >> 4, ml = f & 15;
        size_t oidx = ((size_t)(b * CDIM + c)) * NSEQ + m0 + ml;
        out[oidx] = g * KT_lds[ml * V_STR + c] + ref[oidx];
    }
}

// ---------------------------------------------------------------------------
extern "C" void kernel_launch(void* const* d_in, const int* in_sizes, int n_in,
                              void* d_out, int out_size, void* d_ws, size_t ws_size,
                              hipStream_t stream)
{
    // inputs dict order: inputs, ref, w1, w2, gamma  (inputs feeds only the dead conv -> skipped)
    const float* ref = (const float*)d_in[1];
    const float* w1  = (const float*)d_in[2];
    const float* w2  = (const float*)d_in[3];
    const float* gma = (const float*)d_in[4];
    float* out = (float*)d_out;

    float* XT = (float*)d_ws;                        // [B][N][C] = relu(conv(ref,w1)) transposed
    float* VT = XT + (size_t)4 * NSEQ * CDIM;        // [B][N][C] = relu(conv(ref,w2)) transposed

    dim3 cgrid(16, 32, 4);
    conv3x3_relu_T_kernel<<<cgrid, 256, 0, stream>>>(ref, w1, XT);
    conv3x3_relu_T_kernel<<<cgrid, 256, 0, stream>>>(ref, w2, VT);

    attn_kernel<<<dim3(NSEQ / M_TILE, 4), 256, 0, stream>>>(XT, VT, ref, gma, out);
}

// Round 2
// 1565.888 us; speedup vs baseline: 2.6339x; 2.6339x over previous
//
#include <hip/hip_runtime.h>
#include <math.h>

#define CDIM 256
#define NSEQ 4096
#define HWDIM 64

typedef unsigned short u16;
typedef __attribute__((ext_vector_type(8))) short bf16x8;
typedef __attribute__((ext_vector_type(4))) float f32x4;

__device__ __forceinline__ u16 f2bf(float f) {
    unsigned u = __float_as_uint(f);
    unsigned r = (u + 0x7FFFu + ((u >> 16) & 1u)) >> 16;   // RN-even
    return (u16)r;
}

// ---------------------------------------------------------------------------
// conv3x3 (SAME, stride 1, no bias) + ReLU -> bf16.
// TRANSP=true : y[b][n][co]  (attention Q/K layout)
// TRANSP=false: y[b][co][n]  (attention V layout, natural NCHW)
// block: 256 threads = 16x16 spatial tile; 8 output channels per block
// ---------------------------------------------------------------------------
template <bool TRANSP>
__global__ __launch_bounds__(256)
void conv3x3_relu_kernel(const float* __restrict__ x, const float* __restrict__ w,
                         u16* __restrict__ y)
{
    __shared__ float tile[4 * 18 * 18];
    const int tid = threadIdx.x;
    const int tx = tid & 15, ty = tid >> 4;
    const int tb = blockIdx.x;
    const int y0 = (tb >> 2) << 4;
    const int x0 = (tb & 3) << 4;
    const int cob = blockIdx.y << 3;
    const int b = blockIdx.z;

    float acc[8] = {0.f,0.f,0.f,0.f,0.f,0.f,0.f,0.f};

    for (int cib = 0; cib < CDIM; cib += 4) {
        __syncthreads();
        #pragma unroll
        for (int k = 0; k < 6; ++k) {
            int e = tid + (k << 8);
            if (e < 1296) {
                int cc = e / 324;
                int rem = e - cc * 324;
                int r = rem / 18;
                int cl = rem - r * 18;
                int gy = y0 + r - 1, gx = x0 + cl - 1;
                float v = 0.0f;
                if (gy >= 0 && gy < HWDIM && gx >= 0 && gx < HWDIM)
                    v = x[(((size_t)b * CDIM + (cib + cc)) * HWDIM + gy) * HWDIM + gx];
                tile[e] = v;
            }
        }
        __syncthreads();
        #pragma unroll
        for (int cc = 0; cc < 4; ++cc) {
            float xr[9];
            #pragma unroll
            for (int dy = 0; dy < 3; ++dy)
                #pragma unroll
                for (int dx = 0; dx < 3; ++dx)
                    xr[dy * 3 + dx] = tile[cc * 324 + (ty + dy) * 18 + (tx + dx)];
            #pragma unroll
            for (int co = 0; co < 8; ++co) {
                const float* __restrict__ wp = &w[((size_t)(cob + co) * CDIM + (cib + cc)) * 9];
                acc[co] += xr[0]*wp[0] + xr[1]*wp[1] + xr[2]*wp[2]
                         + xr[3]*wp[3] + xr[4]*wp[4] + xr[5]*wp[5]
                         + xr[6]*wp[6] + xr[7]*wp[7] + xr[8]*wp[8];
            }
        }
    }

    const int n = (y0 + ty) * HWDIM + x0 + tx;
    if (TRANSP) {
        union { u16 h[8]; float4 v; } pk;
        #pragma unroll
        for (int co = 0; co < 8; ++co) pk.h[co] = f2bf(fmaxf(acc[co], 0.f));
        *(float4*)&y[((size_t)b * NSEQ + n) * CDIM + cob] = pk.v;
    } else {
        #pragma unroll
        for (int co = 0; co < 8; ++co)
            y[((size_t)(b * CDIM + cob + co)) * NSEQ + n] = f2bf(fmaxf(acc[co], 0.f));
    }
}

// ---------------------------------------------------------------------------
// Flash self-attention via bf16 MFMA (Q=K=XT[b][n][c], V=Vn[b][c][n]).
// Softmax over keys (valid: Gram score matrix is symmetric).
// out[b,c,m] = gamma * A[m,c] + ref[b,c,m]
// block: 256 threads (4 waves, each owns 16 query rows). KV chunk = 64.
// LDS tiles XOR-swizzled: u16 index = row*stride + (col ^ ((row&7)<<3)).
// ---------------------------------------------------------------------------
#define M_TILE 64
#define NC 64

__global__ __launch_bounds__(256)
void attn_mfma_kernel(const u16* __restrict__ XT, const u16* __restrict__ Vn,
                      const float* __restrict__ ref, const float* __restrict__ gptr,
                      float* __restrict__ out)
{
    __shared__ alignas(16) u16 smem[53248];      // 104 KB
    u16* Qs = smem;                // [64][256] swizzled
    u16* Ks = smem + 16384;        // [64][256] swizzled
    u16* Vs = smem + 32768;        // [256][64] swizzled ([c][n])
    u16* Ps = smem + 49152;        // [64][64]  swizzled

    const int tid = threadIdx.x;
    const int lane = tid & 63;
    const int wv = tid >> 6;       // wave id: owns query rows wv*16 .. +15
    const int lr = lane & 15;      // fragment row/col index
    const int lg = lane >> 4;      // k-group
    const int b = blockIdx.y;
    const int m0 = blockIdx.x * M_TILE;

    const float4* XTg = (const float4*)XT;   // 8 bf16 per float4
    const float4* Vg  = (const float4*)Vn;

    // ---- stage Q tile (once) ----
    #pragma unroll
    for (int i = 0; i < 8; ++i) {
        int f = tid + (i << 8);
        int r = f >> 5, c8 = f & 31;
        float4 v = XTg[(size_t)(b * NSEQ + m0 + r) * 32 + c8];
        *(float4*)&Qs[r * 256 + ((c8 << 3) ^ ((r & 7) << 3))] = v;
    }

    f32x4 o[16] = {};                       // O acc: 16 rows x 256 c per wave
    float mrun[4] = {-INFINITY, -INFINITY, -INFINITY, -INFINITY};
    float lrun[4] = {0.f, 0.f, 0.f, 0.f};

    for (int n0 = 0; n0 < NSEQ; n0 += NC) {
        __syncthreads();                    // prior chunk's readers done
        // ---- stage K chunk [64][256] ----
        #pragma unroll
        for (int i = 0; i < 8; ++i) {
            int f = tid + (i << 8);
            int r = f >> 5, c8 = f & 31;
            float4 v = XTg[(size_t)(b * NSEQ + n0 + r) * 32 + c8];
            *(float4*)&Ks[r * 256 + ((c8 << 3) ^ ((r & 7) << 3))] = v;
        }
        // ---- stage V chunk [256 c][64 n] ----
        #pragma unroll
        for (int i = 0; i < 8; ++i) {
            int f = tid + (i << 8);
            int c = f >> 3, n8 = f & 7;
            float4 v = Vg[((size_t)(b * CDIM + c) * NSEQ + n0) / 8 + n8];
            *(float4*)&Vs[c * 64 + ((n8 << 3) ^ ((c & 7) << 3))] = v;
        }
        __syncthreads();

        // ---- QK^T: per wave 16 m-rows x 64 keys, K-dim 256 ----
        f32x4 s[4] = {};
        const int rowQ = wv * 16 + lr;
        #pragma unroll
        for (int kk = 0; kk < 8; ++kk) {
            const int ca = ((kk << 5) + (lg << 3)) ^ ((lr & 7) << 3);
            bf16x8 a = *(const bf16x8*)&Qs[rowQ * 256 + ca];
            #pragma unroll
            for (int t = 0; t < 4; ++t) {
                bf16x8 kb = *(const bf16x8*)&Ks[(t * 16 + lr) * 256 + ca];
                s[t] = __builtin_amdgcn_mfma_f32_16x16x32_bf16(a, kb, s[t], 0, 0, 0);
            }
        }

        // ---- online softmax (rows m = wv*16 + lg*4 + r; cols n = t*16 + lr) ----
        #pragma unroll
        for (int r = 0; r < 4; ++r) {
            float v0 = s[0][r], v1 = s[1][r], v2 = s[2][r], v3 = s[3][r];
            float cm = fmaxf(fmaxf(v0, v1), fmaxf(v2, v3));
            cm = fmaxf(cm, __shfl_xor(cm, 1));
            cm = fmaxf(cm, __shfl_xor(cm, 2));
            cm = fmaxf(cm, __shfl_xor(cm, 4));
            cm = fmaxf(cm, __shfl_xor(cm, 8));
            float mnew = fmaxf(mrun[r], cm);
            float al = __expf(mrun[r] - mnew);          // first chunk: exp(-inf)=0
            float p0 = __expf(v0 - mnew), p1 = __expf(v1 - mnew);
            float p2 = __expf(v2 - mnew), p3 = __expf(v3 - mnew);
            float sm = p0 + p1 + p2 + p3;
            sm += __shfl_xor(sm, 1);
            sm += __shfl_xor(sm, 2);
            sm += __shfl_xor(sm, 4);
            sm += __shfl_xor(sm, 8);
            lrun[r] = lrun[r] * al + sm;
            mrun[r] = mnew;
            const int mrow = wv * 16 + lg * 4 + r;
            const int swz = (mrow & 7) << 3;
            Ps[mrow * 64 + ((     lr) ^ swz)] = f2bf(p0);
            Ps[mrow * 64 + ((16 + lr) ^ swz)] = f2bf(p1);
            Ps[mrow * 64 + ((32 + lr) ^ swz)] = f2bf(p2);
            Ps[mrow * 64 + ((48 + lr) ^ swz)] = f2bf(p3);
            #pragma unroll
            for (int cs = 0; cs < 16; ++cs) o[cs][r] *= al;
        }

        // ---- PV: O[m][c] += P[m][n] * V[n][c]  (wave-local P, in-order DS) ----
        #pragma unroll
        for (int ks = 0; ks < 2; ++ks) {
            const int ca = ((ks << 5) + (lg << 3)) ^ ((lr & 7) << 3);
            bf16x8 pa = *(const bf16x8*)&Ps[(wv * 16 + lr) * 64 + ca];
            #pragma unroll
            for (int cs = 0; cs < 16; ++cs) {
                bf16x8 vb = *(const bf16x8*)&Vs[(cs * 16 + lr) * 64 + ca];
                o[cs] = __builtin_amdgcn_mfma_f32_16x16x32_bf16(pa, vb, o[cs], 0, 0, 0);
            }
        }
    }

    // ---- epilogue: normalize, LDS transpose, fused gamma*A + ref ----
    __syncthreads();
    float* olds = (float*)smem;            // [64][257] f32 (65.8 KB, overlays Q/K/V)
    #pragma unroll
    for (int r = 0; r < 4; ++r) {
        float inv = 1.0f / lrun[r];
        const int mrow = wv * 16 + lg * 4 + r;
        #pragma unroll
        for (int cs = 0; cs < 16; ++cs)
            olds[mrow * 257 + cs * 16 + lr] = o[cs][r] * inv;
    }
    __syncthreads();
    const float g = gptr[0];
    #pragma unroll 8
    for (int i = 0; i < 64; ++i) {
        int f = tid + (i << 8);
        int c = f >> 6, ml = f & 63;
        size_t oi = ((size_t)(b * CDIM + c)) * NSEQ + m0 + ml;
        out[oi] = g * olds[ml * 257 + c] + ref[oi];
    }
}

// ---------------------------------------------------------------------------
extern "C" void kernel_launch(void* const* d_in, const int* in_sizes, int n_in,
                              void* d_out, int out_size, void* d_ws, size_t ws_size,
                              hipStream_t stream)
{
    // dict order: inputs, ref, w1, w2, gamma (dead conv on `inputs` skipped)
    const float* ref = (const float*)d_in[1];
    const float* w1  = (const float*)d_in[2];
    const float* w2  = (const float*)d_in[3];
    const float* gma = (const float*)d_in[4];
    float* out = (float*)d_out;

    u16* XT = (u16*)d_ws;                          // [B][N][C] bf16 (Q=K)
    u16* Vn = XT + (size_t)4 * NSEQ * CDIM;        // [B][C][N] bf16 (V)

    dim3 cgrid(16, 32, 4);
    conv3x3_relu_kernel<true ><<<cgrid, 256, 0, stream>>>(ref, w1, XT);
    conv3x3_relu_kernel<false><<<cgrid, 256, 0, stream>>>(ref, w2, Vn);

    attn_mfma_kernel<<<dim3(NSEQ / M_TILE, 4), 256, 0, stream>>>(XT, Vn, ref, gma, out);
}

// Round 3
// 567.326 us; speedup vs baseline: 7.2698x; 2.7601x over previous
//
#include <hip/hip_runtime.h>
#include <math.h>

#define CDIM 256
#define NSEQ 4096
#define HWDIM 64
#define PPIX 4356   // 66*66 padded pixels

typedef unsigned short u16;
typedef __attribute__((ext_vector_type(8))) short bf16x8;
typedef __attribute__((ext_vector_type(4))) float f32x4;

__device__ __forceinline__ u16 f2bf(float f) {
    unsigned u = __float_as_uint(f);
    unsigned r = (u + 0x7FFFu + ((u >> 16) & 1u)) >> 16;   // RN-even
    return (u16)r;
}

// ---------------------------------------------------------------------------
// pad+transpose: ref fp32 NCHW [b][c][64][64] -> padded bf16 [b][pp][c],
// pp=(y+1)*66+(x+1); border stays zero (memset'd by launcher).
// block: 256 thr; grid (64 y, 4 c-chunks, 4 b). LDS transpose [64c][64x].
// ---------------------------------------------------------------------------
__global__ __launch_bounds__(256)
void pad_transpose_kernel(const float* __restrict__ x, u16* __restrict__ padded)
{
    __shared__ float lds[64 * 65];
    const int tid = threadIdx.x;
    const int y = blockIdx.x, c0 = blockIdx.y << 6, b = blockIdx.z;
    #pragma unroll
    for (int i = 0; i < 16; ++i) {
        int f = tid + (i << 8);
        int c = f >> 6, xx = f & 63;
        lds[c * 65 + xx] = x[(((size_t)(b * CDIM + c0 + c)) * HWDIM + y) * HWDIM + xx];
    }
    __syncthreads();
    #pragma unroll
    for (int i = 0; i < 2; ++i) {
        int f = tid + (i << 8);
        int xx = f >> 3, c8 = f & 7;
        union { u16 h[8]; float4 v; } pk;
        #pragma unroll
        for (int j = 0; j < 8; ++j) pk.h[j] = f2bf(lds[(c8 * 8 + j) * 65 + xx]);
        *(float4*)&padded[((size_t)b * PPIX + (y + 1) * 66 + (xx + 1)) * CDIM + c0 + (c8 << 3)] = pk.v;
    }
}

// ---------------------------------------------------------------------------
// weight prepack: w fp32 [co][ci][3][3] -> wk bf16 [kyx][co][ci]
// ---------------------------------------------------------------------------
__global__ __launch_bounds__(256)
void w_prepack_kernel(const float* __restrict__ w, u16* __restrict__ wk)
{
    int t = (blockIdx.x << 8) + threadIdx.x;     // 65536 = co*256+ci
    const float* wp = w + (size_t)t * 9;
    #pragma unroll
    for (int j = 0; j < 9; ++j) wk[j * 65536 + t] = f2bf(wp[j]);
}

// ---------------------------------------------------------------------------
// conv3x3+ReLU as 9 offset-GEMMs over the padded image. bf16 MFMA, fp32 acc.
// Tile: 64 pixels (one image row) x 128 co; K = 9*256 in 36 steps of 64.
// OA=true : D[n][co] -> direct 8B stores to Vn[b][co][n]   (conv2)
// OA=false: D[co][n] -> direct 8B stores to XT[b][n][co]   (conv1)
// grid (2 co-tiles, 64 rows, 4 b) = 512 blocks, 256 thr (4 waves, wave=co-split)
// ---------------------------------------------------------------------------
template <bool OA>
__global__ __launch_bounds__(256)
void conv_mfma_kernel(const u16* __restrict__ padded, const u16* __restrict__ wk,
                      u16* __restrict__ out)
{
    __shared__ alignas(16) u16 Xs[64 * 64];    // [x][ci] swizzled, 8 KB
    __shared__ alignas(16) u16 Ws[128 * 64];   // [co][ci] swizzled, 16 KB

    const int tid = threadIdx.x;
    const int lane = tid & 63, wv = tid >> 6;
    const int lr = lane & 15, lg = lane >> 4;
    const int cb = blockIdx.x << 7;
    const int y0 = blockIdx.y;                 // image row; m0 = y0*64
    const int b = blockIdx.z;

    constexpr int MF = OA ? 4 : 2;
    constexpr int NF = OA ? 2 : 4;
    f32x4 acc[MF][NF] = {};

    for (int t = 0; t < 36; ++t) {
        const int kyx = t >> 2, cib = (t & 3) << 6;
        const int ky = kyx / 3, kx = kyx - ky * 3;
        __syncthreads();
        // stage X: one padded image row segment [64 x][64 ci]
        #pragma unroll
        for (int i = 0; i < 2; ++i) {
            int f = tid + (i << 8);
            int r = f >> 3, c8 = f & 7;
            int pp = (y0 + ky) * 66 + r + kx;
            float4 v = *(const float4*)&padded[((size_t)b * PPIX + pp) * CDIM + cib + (c8 << 3)];
            *(float4*)&Xs[(r << 6) + ((c8 << 3) ^ ((r & 7) << 3))] = v;
        }
        // stage W: [128 co][64 ci]
        #pragma unroll
        for (int i = 0; i < 4; ++i) {
            int f = tid + (i << 8);
            int r = f >> 3, c8 = f & 7;
            float4 v = *(const float4*)&wk[((size_t)kyx << 16) + (size_t)(cb + r) * 256 + cib + (c8 << 3)];
            *(float4*)&Ws[(r << 6) + ((c8 << 3) ^ ((r & 7) << 3))] = v;
        }
        __syncthreads();
        #pragma unroll
        for (int kk = 0; kk < 2; ++kk) {
            const int ca = ((kk << 5) + (lg << 3)) ^ ((lr & 7) << 3);
            if constexpr (OA) {
                bf16x8 a[4], bb[2];
                #pragma unroll
                for (int mf = 0; mf < 4; ++mf)
                    a[mf] = *(const bf16x8*)&Xs[((mf * 16 + lr) << 6) + ca];
                #pragma unroll
                for (int nf = 0; nf < 2; ++nf)
                    bb[nf] = *(const bf16x8*)&Ws[((wv * 32 + nf * 16 + lr) << 6) + ca];
                #pragma unroll
                for (int mf = 0; mf < 4; ++mf)
                    #pragma unroll
                    for (int nf = 0; nf < 2; ++nf)
                        acc[mf][nf] = __builtin_amdgcn_mfma_f32_16x16x32_bf16(a[mf], bb[nf], acc[mf][nf], 0, 0, 0);
            } else {
                bf16x8 a[2], bb[4];
                #pragma unroll
                for (int mf = 0; mf < 2; ++mf)
                    a[mf] = *(const bf16x8*)&Ws[((wv * 32 + mf * 16 + lr) << 6) + ca];
                #pragma unroll
                for (int nf = 0; nf < 4; ++nf)
                    bb[nf] = *(const bf16x8*)&Xs[((nf * 16 + lr) << 6) + ca];
                #pragma unroll
                for (int mf = 0; mf < 2; ++mf)
                    #pragma unroll
                    for (int nf = 0; nf < 4; ++nf)
                        acc[mf][nf] = __builtin_amdgcn_mfma_f32_16x16x32_bf16(a[mf], bb[nf], acc[mf][nf], 0, 0, 0);
            }
        }
    }

    const int m0 = y0 << 6;
    if constexpr (OA) {
        // D[n][co]: lane frag = 4 consecutive n at fixed co -> Vn[b][co][n]
        #pragma unroll
        for (int mf = 0; mf < 4; ++mf)
            #pragma unroll
            for (int nf = 0; nf < 2; ++nf) {
                int nb = m0 + mf * 16 + lg * 4;
                int co = cb + wv * 32 + nf * 16 + lr;
                union { u16 h[4]; uint2 v; } pk;
                #pragma unroll
                for (int j = 0; j < 4; ++j) pk.h[j] = f2bf(fmaxf(acc[mf][nf][j], 0.f));
                *(uint2*)&out[((size_t)(b * CDIM + co)) * NSEQ + nb] = pk.v;
            }
    } else {
        // D[co][n]: lane frag = 4 consecutive co at fixed n -> XT[b][n][co]
        #pragma unroll
        for (int mf = 0; mf < 2; ++mf)
            #pragma unroll
            for (int nf = 0; nf < 4; ++nf) {
                int cob = cb + wv * 32 + mf * 16 + lg * 4;
                int n = m0 + nf * 16 + lr;
                union { u16 h[4]; uint2 v; } pk;
                #pragma unroll
                for (int j = 0; j < 4; ++j) pk.h[j] = f2bf(fmaxf(acc[mf][nf][j], 0.f));
                *(uint2*)&out[((size_t)(b * NSEQ + n)) * CDIM + cob] = pk.v;
            }
    }
}

// ---------------------------------------------------------------------------
// Flash self-attention via bf16 MFMA (Q=K=XT[b][n][c], V=Vn[b][c][n]).
// Softmax over keys (valid: Gram score matrix is symmetric).
// out[b,c,m] = gamma * A[m,c] + ref[b,c,m]
// ---------------------------------------------------------------------------
#define M_TILE 64
#define NC 64

__global__ __launch_bounds__(256)
void attn_mfma_kernel(const u16* __restrict__ XT, const u16* __restrict__ Vn,
                      const float* __restrict__ ref, const float* __restrict__ gptr,
                      float* __restrict__ out)
{
    __shared__ alignas(16) u16 smem[53248];      // 104 KB
    u16* Qs = smem;                // [64][256] swizzled
    u16* Ks = smem + 16384;        // [64][256] swizzled
    u16* Vs = smem + 32768;        // [256][64] swizzled ([c][n])
    u16* Ps = smem + 49152;        // [64][64]  swizzled

    const int tid = threadIdx.x;
    const int lane = tid & 63;
    const int wv = tid >> 6;       // wave id: owns query rows wv*16 .. +15
    const int lr = lane & 15;
    const int lg = lane >> 4;
    const int b = blockIdx.y;
    const int m0 = blockIdx.x * M_TILE;

    const float4* XTg = (const float4*)XT;   // 8 bf16 per float4
    const float4* Vg  = (const float4*)Vn;

    #pragma unroll
    for (int i = 0; i < 8; ++i) {
        int f = tid + (i << 8);
        int r = f >> 5, c8 = f & 31;
        float4 v = XTg[(size_t)(b * NSEQ + m0 + r) * 32 + c8];
        *(float4*)&Qs[r * 256 + ((c8 << 3) ^ ((r & 7) << 3))] = v;
    }

    f32x4 o[16] = {};
    float mrun[4] = {-INFINITY, -INFINITY, -INFINITY, -INFINITY};
    float lrun[4] = {0.f, 0.f, 0.f, 0.f};

    for (int n0 = 0; n0 < NSEQ; n0 += NC) {
        __syncthreads();
        #pragma unroll
        for (int i = 0; i < 8; ++i) {
            int f = tid + (i << 8);
            int r = f >> 5, c8 = f & 31;
            float4 v = XTg[(size_t)(b * NSEQ + n0 + r) * 32 + c8];
            *(float4*)&Ks[r * 256 + ((c8 << 3) ^ ((r & 7) << 3))] = v;
        }
        #pragma unroll
        for (int i = 0; i < 8; ++i) {
            int f = tid + (i << 8);
            int c = f >> 3, n8 = f & 7;
            float4 v = Vg[((size_t)(b * CDIM + c) * NSEQ + n0) / 8 + n8];
            *(float4*)&Vs[c * 64 + ((n8 << 3) ^ ((c & 7) << 3))] = v;
        }
        __syncthreads();

        f32x4 s[4] = {};
        const int rowQ = wv * 16 + lr;
        #pragma unroll
        for (int kk = 0; kk < 8; ++kk) {
            const int ca = ((kk << 5) + (lg << 3)) ^ ((lr & 7) << 3);
            bf16x8 a = *(const bf16x8*)&Qs[rowQ * 256 + ca];
            #pragma unroll
            for (int t = 0; t < 4; ++t) {
                bf16x8 kb = *(const bf16x8*)&Ks[(t * 16 + lr) * 256 + ca];
                s[t] = __builtin_amdgcn_mfma_f32_16x16x32_bf16(a, kb, s[t], 0, 0, 0);
            }
        }

        #pragma unroll
        for (int r = 0; r < 4; ++r) {
            float v0 = s[0][r], v1 = s[1][r], v2 = s[2][r], v3 = s[3][r];
            float cm = fmaxf(fmaxf(v0, v1), fmaxf(v2, v3));
            cm = fmaxf(cm, __shfl_xor(cm, 1));
            cm = fmaxf(cm, __shfl_xor(cm, 2));
            cm = fmaxf(cm, __shfl_xor(cm, 4));
            cm = fmaxf(cm, __shfl_xor(cm, 8));
            float mnew = fmaxf(mrun[r], cm);
            float al = __expf(mrun[r] - mnew);
            float p0 = __expf(v0 - mnew), p1 = __expf(v1 - mnew);
            float p2 = __expf(v2 - mnew), p3 = __expf(v3 - mnew);
            float sm = p0 + p1 + p2 + p3;
            sm += __shfl_xor(sm, 1);
            sm += __shfl_xor(sm, 2);
            sm += __shfl_xor(sm, 4);
            sm += __shfl_xor(sm, 8);
            lrun[r] = lrun[r] * al + sm;
            mrun[r] = mnew;
            const int mrow = wv * 16 + lg * 4 + r;
            const int swz = (mrow & 7) << 3;
            Ps[mrow * 64 + ((     lr) ^ swz)] = f2bf(p0);
            Ps[mrow * 64 + ((16 + lr) ^ swz)] = f2bf(p1);
            Ps[mrow * 64 + ((32 + lr) ^ swz)] = f2bf(p2);
            Ps[mrow * 64 + ((48 + lr) ^ swz)] = f2bf(p3);
            #pragma unroll
            for (int cs = 0; cs < 16; ++cs) o[cs][r] *= al;
        }

        #pragma unroll
        for (int ks = 0; ks < 2; ++ks) {
            const int ca = ((ks << 5) + (lg << 3)) ^ ((lr & 7) << 3);
            bf16x8 pa = *(const bf16x8*)&Ps[(wv * 16 + lr) * 64 + ca];
            #pragma unroll
            for (int cs = 0; cs < 16; ++cs) {
                bf16x8 vb = *(const bf16x8*)&Vs[(cs * 16 + lr) * 64 + ca];
                o[cs] = __builtin_amdgcn_mfma_f32_16x16x32_bf16(pa, vb, o[cs], 0, 0, 0);
            }
        }
    }

    __syncthreads();
    float* olds = (float*)smem;            // [64][257] f32
    #pragma unroll
    for (int r = 0; r < 4; ++r) {
        float inv = 1.0f / lrun[r];
        const int mrow = wv * 16 + lg * 4 + r;
        #pragma unroll
        for (int cs = 0; cs < 16; ++cs)
            olds[mrow * 257 + cs * 16 + lr] = o[cs][r] * inv;
    }
    __syncthreads();
    const float g = gptr[0];
    #pragma unroll 8
    for (int i = 0; i < 64; ++i) {
        int f = tid + (i << 8);
        int c = f >> 6, ml = f & 63;
        size_t oi = ((size_t)(b * CDIM + c)) * NSEQ + m0 + ml;
        out[oi] = g * olds[ml * 257 + c] + ref[oi];
    }
}

// ---------------------------------------------------------------------------
extern "C" void kernel_launch(void* const* d_in, const int* in_sizes, int n_in,
                              void* d_out, int out_size, void* d_ws, size_t ws_size,
                              hipStream_t stream)
{
    // dict order: inputs, ref, w1, w2, gamma (dead conv on `inputs` skipped)
    const float* ref = (const float*)d_in[1];
    const float* w1  = (const float*)d_in[2];
    const float* w2  = (const float*)d_in[3];
    const float* gma = (const float*)d_in[4];
    float* out = (float*)d_out;

    u16* padded = (u16*)d_ws;                                  // [B][4356][256] bf16
    u16* wk1 = padded + (size_t)4 * PPIX * CDIM;               // [9][256][256] bf16
    u16* wk2 = wk1 + (size_t)9 * 65536;
    u16* XT  = wk2 + (size_t)9 * 65536;                        // [B][N][C] bf16 (Q=K)
    u16* Vn  = XT + (size_t)4 * NSEQ * CDIM;                   // [B][C][N] bf16 (V)

    hipMemsetAsync(padded, 0, (size_t)4 * PPIX * CDIM * sizeof(u16), stream);
    pad_transpose_kernel<<<dim3(64, 4, 4), 256, 0, stream>>>(ref, padded);
    w_prepack_kernel<<<dim3(256), 256, 0, stream>>>(w1, wk1);
    w_prepack_kernel<<<dim3(256), 256, 0, stream>>>(w2, wk2);

    dim3 cgrid(2, 64, 4);
    conv_mfma_kernel<false><<<cgrid, 256, 0, stream>>>(padded, wk1, XT);  // -> XT
    conv_mfma_kernel<true ><<<cgrid, 256, 0, stream>>>(padded, wk2, Vn);  // -> Vn

    attn_mfma_kernel<<<dim3(NSEQ / M_TILE, 4), 256, 0, stream>>>(XT, Vn, ref, gma, out);
}

// Round 4
// 276.529 us; speedup vs baseline: 14.9148x; 2.0516x over previous
//
#include <hip/hip_runtime.h>
#include <math.h>

#define CDIM 256
#define NSEQ 4096
#define HWDIM 64
#define PPIX 4356   // 66*66 padded pixels

typedef unsigned short u16;
typedef __attribute__((ext_vector_type(8))) short bf16x8;
typedef __attribute__((ext_vector_type(4))) float f32x4;

__device__ __forceinline__ u16 f2bf(float f) {
    unsigned u = __float_as_uint(f);
    unsigned r = (u + 0x7FFFu + ((u >> 16) & 1u)) >> 16;   // RN-even
    return (u16)r;
}

// async global->LDS, 16B per lane; LDS dest = wave-uniform base + lane*16
__device__ __forceinline__ void gload_lds16(const u16* g, u16* l) {
    __builtin_amdgcn_global_load_lds(
        (const __attribute__((address_space(1))) unsigned int*)g,
        (__attribute__((address_space(3))) unsigned int*)l, 16, 0, 0);
}

// ---------------------------------------------------------------------------
// pad+transpose: ref fp32 NCHW -> padded bf16 [b][pp][c], pp=(y+1)*66+(x+1)
// ---------------------------------------------------------------------------
__global__ __launch_bounds__(256)
void pad_transpose_kernel(const float* __restrict__ x, u16* __restrict__ padded)
{
    __shared__ float lds[64 * 65];
    const int tid = threadIdx.x;
    const int y = blockIdx.x, c0 = blockIdx.y << 6, b = blockIdx.z;
    #pragma unroll
    for (int i = 0; i < 16; ++i) {
        int f = tid + (i << 8);
        int c = f >> 6, xx = f & 63;
        lds[c * 65 + xx] = x[(((size_t)(b * CDIM + c0 + c)) * HWDIM + y) * HWDIM + xx];
    }
    __syncthreads();
    #pragma unroll
    for (int i = 0; i < 2; ++i) {
        int f = tid + (i << 8);
        int xx = f >> 3, c8 = f & 7;
        union { u16 h[8]; float4 v; } pk;
        #pragma unroll
        for (int j = 0; j < 8; ++j) pk.h[j] = f2bf(lds[(c8 * 8 + j) * 65 + xx]);
        *(float4*)&padded[((size_t)b * PPIX + (y + 1) * 66 + (xx + 1)) * CDIM + c0 + (c8 << 3)] = pk.v;
    }
}

// ---------------------------------------------------------------------------
// weight prepack: w fp32 [co][ci][3][3] -> wk bf16 [kyx][co][ci]
// ---------------------------------------------------------------------------
__global__ __launch_bounds__(256)
void w_prepack_kernel(const float* __restrict__ w, u16* __restrict__ wk)
{
    int t = (blockIdx.x << 8) + threadIdx.x;
    const float* wp = w + (size_t)t * 9;
    #pragma unroll
    for (int j = 0; j < 9; ++j) wk[j * 65536 + t] = f2bf(wp[j]);
}

// ---------------------------------------------------------------------------
// conv3x3+ReLU as 9 offset-GEMMs over the padded image. bf16 MFMA, fp32 acc.
// OA=true : D[n][co] -> Vn[b][co][n]   (conv2)
// OA=false: D[co][n] -> XT[b][n][co]   (conv1)
// ---------------------------------------------------------------------------
template <bool OA>
__global__ __launch_bounds__(256)
void conv_mfma_kernel(const u16* __restrict__ padded, const u16* __restrict__ wk,
                      u16* __restrict__ out)
{
    __shared__ alignas(16) u16 Xs[64 * 64];
    __shared__ alignas(16) u16 Ws[128 * 64];

    const int tid = threadIdx.x;
    const int lane = tid & 63, wv = tid >> 6;
    const int lr = lane & 15, lg = lane >> 4;
    const int cb = blockIdx.x << 7;
    const int y0 = blockIdx.y;
    const int b = blockIdx.z;

    constexpr int MF = OA ? 4 : 2;
    constexpr int NF = OA ? 2 : 4;
    f32x4 acc[MF][NF] = {};

    for (int t = 0; t < 36; ++t) {
        const int kyx = t >> 2, cib = (t & 3) << 6;
        const int ky = kyx / 3, kx = kyx - ky * 3;
        __syncthreads();
        #pragma unroll
        for (int i = 0; i < 2; ++i) {
            int f = tid + (i << 8);
            int r = f >> 3, c8 = f & 7;
            int pp = (y0 + ky) * 66 + r + kx;
            float4 v = *(const float4*)&padded[((size_t)b * PPIX + pp) * CDIM + cib + (c8 << 3)];
            *(float4*)&Xs[(r << 6) + ((c8 << 3) ^ ((r & 7) << 3))] = v;
        }
        #pragma unroll
        for (int i = 0; i < 4; ++i) {
            int f = tid + (i << 8);
            int r = f >> 3, c8 = f & 7;
            float4 v = *(const float4*)&wk[((size_t)kyx << 16) + (size_t)(cb + r) * 256 + cib + (c8 << 3)];
            *(float4*)&Ws[(r << 6) + ((c8 << 3) ^ ((r & 7) << 3))] = v;
        }
        __syncthreads();
        #pragma unroll
        for (int kk = 0; kk < 2; ++kk) {
            const int ca = ((kk << 5) + (lg << 3)) ^ ((lr & 7) << 3);
            if constexpr (OA) {
                bf16x8 a[4], bb[2];
                #pragma unroll
                for (int mf = 0; mf < 4; ++mf)
                    a[mf] = *(const bf16x8*)&Xs[((mf * 16 + lr) << 6) + ca];
                #pragma unroll
                for (int nf = 0; nf < 2; ++nf)
                    bb[nf] = *(const bf16x8*)&Ws[((wv * 32 + nf * 16 + lr) << 6) + ca];
                #pragma unroll
                for (int mf = 0; mf < 4; ++mf)
                    #pragma unroll
                    for (int nf = 0; nf < 2; ++nf)
                        acc[mf][nf] = __builtin_amdgcn_mfma_f32_16x16x32_bf16(a[mf], bb[nf], acc[mf][nf], 0, 0, 0);
            } else {
                bf16x8 a[2], bb[4];
                #pragma unroll
                for (int mf = 0; mf < 2; ++mf)
                    a[mf] = *(const bf16x8*)&Ws[((wv * 32 + mf * 16 + lr) << 6) + ca];
                #pragma unroll
                for (int nf = 0; nf < 4; ++nf)
                    bb[nf] = *(const bf16x8*)&Xs[((nf * 16 + lr) << 6) + ca];
                #pragma unroll
                for (int mf = 0; mf < 2; ++mf)
                    #pragma unroll
                    for (int nf = 0; nf < 4; ++nf)
                        acc[mf][nf] = __builtin_amdgcn_mfma_f32_16x16x32_bf16(a[mf], bb[nf], acc[mf][nf], 0, 0, 0);
            }
        }
    }

    const int m0 = y0 << 6;
    if constexpr (OA) {
        #pragma unroll
        for (int mf = 0; mf < 4; ++mf)
            #pragma unroll
            for (int nf = 0; nf < 2; ++nf) {
                int nb = m0 + mf * 16 + lg * 4;
                int co = cb + wv * 32 + nf * 16 + lr;
                union { u16 h[4]; uint2 v; } pk;
                #pragma unroll
                for (int j = 0; j < 4; ++j) pk.h[j] = f2bf(fmaxf(acc[mf][nf][j], 0.f));
                *(uint2*)&out[((size_t)(b * CDIM + co)) * NSEQ + nb] = pk.v;
            }
    } else {
        #pragma unroll
        for (int mf = 0; mf < 2; ++mf)
            #pragma unroll
            for (int nf = 0; nf < 4; ++nf) {
                int cob = cb + wv * 32 + mf * 16 + lg * 4;
                int n = m0 + nf * 16 + lr;
                union { u16 h[4]; uint2 v; } pk;
                #pragma unroll
                for (int j = 0; j < 4; ++j) pk.h[j] = f2bf(fmaxf(acc[mf][nf][j], 0.f));
                *(uint2*)&out[((size_t)(b * NSEQ + n)) * CDIM + cob] = pk.v;
            }
    }
}

// ---------------------------------------------------------------------------
// Flash self-attention, bf16 MFMA, double-buffered K/V via global_load_lds.
// Q in registers. One barrier per 64-key chunk; next chunk's loads are in
// flight across the whole compute phase (T3-minimal 2-phase pipeline).
// LDS content is XOR-swizzled via pre-swizzled GLOBAL source (T21): linear
// dest group g of row r receives source group g^(r&7); reads XOR as before.
// ---------------------------------------------------------------------------
#define M_TILE 64
#define NC 64

// stage one K/V chunk (keys n0..n0+63) into Kb/Vb; 16 gload_lds per wave
__device__ __forceinline__ void stage_chunk(const u16* __restrict__ XT, const u16* __restrict__ Vn,
                                            u16* Kb, u16* Vb, int b, int n0, int wv, int lane)
{
    #pragma unroll
    for (int i = 0; i < 8; ++i) {
        int f = ((i << 2) + wv) << 6;          // wave-uniform 16B-unit base
        int fl = f + lane;
        int r = fl >> 5;                        // key row 0..63
        int gsw = (fl & 31) ^ (r & 7);          // pre-swizzled source group
        gload_lds16(&XT[(size_t)(b * NSEQ + n0 + r) * CDIM + (gsw << 3)], Kb + (f << 3));
    }
    #pragma unroll
    for (int i = 0; i < 8; ++i) {
        int f = ((i << 2) + wv) << 6;
        int fl = f + lane;
        int r = fl >> 3;                        // channel row 0..255
        int gsw = (fl & 7) ^ (r & 7);
        gload_lds16(&Vn[(size_t)(b * CDIM + r) * NSEQ + n0 + (gsw << 3)], Vb + (f << 3));
    }
}

__global__ __launch_bounds__(256)
void attn_mfma_kernel(const u16* __restrict__ XT, const u16* __restrict__ Vn,
                      const float* __restrict__ ref, const float* __restrict__ gptr,
                      float* __restrict__ out)
{
    __shared__ alignas(16) u16 smem[69632];     // 136 KB
    // [Ks0 16384][Ks1 16384][Vs0 16384][Vs1 16384][Ps 4096]
    u16* Ps = smem + 65536;

    const int tid = threadIdx.x;
    const int lane = tid & 63;
    const int wv = tid >> 6;
    const int lr = lane & 15;
    const int lg = lane >> 4;
    const int b = blockIdx.x;                   // grid (4, 64): 2 XCDs per batch
    const int m0 = blockIdx.y * M_TILE;

    // Q in registers: lane holds A-frags for row m0 + wv*16 + lr
    bf16x8 qreg[8];
    {
        const u16* qrow = &XT[(size_t)(b * NSEQ + m0 + wv * 16 + lr) * CDIM + (lg << 3)];
        #pragma unroll
        for (int kk = 0; kk < 8; ++kk)
            qreg[kk] = *(const bf16x8*)(qrow + (kk << 5));
    }

    f32x4 o[16] = {};
    float mrun[4] = {-INFINITY, -INFINITY, -INFINITY, -INFINITY};
    float lrun[4] = {0.f, 0.f, 0.f, 0.f};

    // prologue: stage chunk 0 into buffer 0
    stage_chunk(XT, Vn, smem, smem + 32768, b, 0, wv, lane);
    __syncthreads();

    int cur = 0;
    for (int n0 = 0; n0 < NSEQ; n0 += NC) {
        // issue next chunk's loads (complete during compute below)
        if (n0 + NC < NSEQ)
            stage_chunk(XT, Vn, smem + (cur ^ 1) * 16384, smem + 32768 + (cur ^ 1) * 16384,
                        b, n0 + NC, wv, lane);

        const u16* Kc = smem + cur * 16384;
        const u16* Vc = smem + 32768 + cur * 16384;

        // ---- QK^T ----
        f32x4 s[4] = {};
        #pragma unroll
        for (int kk = 0; kk < 8; ++kk) {
            const int ca = ((kk << 5) + (lg << 3)) ^ ((lr & 7) << 3);
            #pragma unroll
            for (int t = 0; t < 4; ++t) {
                bf16x8 kb = *(const bf16x8*)&Kc[(t * 16 + lr) * 256 + ca];
                s[t] = __builtin_amdgcn_mfma_f32_16x16x32_bf16(qreg[kk], kb, s[t], 0, 0, 0);
            }
        }

        // ---- online softmax ----
        #pragma unroll
        for (int r = 0; r < 4; ++r) {
            float v0 = s[0][r], v1 = s[1][r], v2 = s[2][r], v3 = s[3][r];
            float cm = fmaxf(fmaxf(v0, v1), fmaxf(v2, v3));
            cm = fmaxf(cm, __shfl_xor(cm, 1));
            cm = fmaxf(cm, __shfl_xor(cm, 2));
            cm = fmaxf(cm, __shfl_xor(cm, 4));
            cm = fmaxf(cm, __shfl_xor(cm, 8));
            float mnew = fmaxf(mrun[r], cm);
            float al = __expf(mrun[r] - mnew);
            float p0 = __expf(v0 - mnew), p1 = __expf(v1 - mnew);
            float p2 = __expf(v2 - mnew), p3 = __expf(v3 - mnew);
            float sm = p0 + p1 + p2 + p3;
            sm += __shfl_xor(sm, 1);
            sm += __shfl_xor(sm, 2);
            sm += __shfl_xor(sm, 4);
            sm += __shfl_xor(sm, 8);
            lrun[r] = lrun[r] * al + sm;
            mrun[r] = mnew;
            const int mrow = wv * 16 + lg * 4 + r;
            const int swz = (mrow & 7) << 3;
            Ps[mrow * 64 + ((     lr) ^ swz)] = f2bf(p0);
            Ps[mrow * 64 + ((16 + lr) ^ swz)] = f2bf(p1);
            Ps[mrow * 64 + ((32 + lr) ^ swz)] = f2bf(p2);
            Ps[mrow * 64 + ((48 + lr) ^ swz)] = f2bf(p3);
            #pragma unroll
            for (int cs = 0; cs < 16; ++cs) o[cs][r] *= al;
        }

        // ---- PV (wave-local P round-trip; same-wave DS ops in-order) ----
        #pragma unroll
        for (int ks = 0; ks < 2; ++ks) {
            const int ca = ((ks << 5) + (lg << 3)) ^ ((lr & 7) << 3);
            bf16x8 pa = *(const bf16x8*)&Ps[(wv * 16 + lr) * 64 + ca];
            #pragma unroll
            for (int cs = 0; cs < 16; ++cs) {
                bf16x8 vb = *(const bf16x8*)&Vc[(cs * 16 + lr) * 64 + ca];
                o[cs] = __builtin_amdgcn_mfma_f32_16x16x32_bf16(pa, vb, o[cs], 0, 0, 0);
            }
        }

        __syncthreads();   // drains vmcnt(0): next buffer ready; this buffer reusable
        cur ^= 1;
    }

    // ---- epilogue: normalize, LDS transpose, fused gamma*A + ref ----
    float* olds = (float*)smem;            // [64][257] f32 overlay
    #pragma unroll
    for (int r = 0; r < 4; ++r) {
        float inv = 1.0f / lrun[r];
        const int mrow = wv * 16 + lg * 4 + r;
        #pragma unroll
        for (int cs = 0; cs < 16; ++cs)
            olds[mrow * 257 + cs * 16 + lr] = o[cs][r] * inv;
    }
    __syncthreads();
    const float g = gptr[0];
    #pragma unroll 8
    for (int i = 0; i < 64; ++i) {
        int f = tid + (i << 8);
        int c = f >> 6, ml = f & 63;
        size_t oi = ((size_t)(b * CDIM + c)) * NSEQ + m0 + ml;
        out[oi] = g * olds[ml * 257 + c] + ref[oi];
    }
}

// ---------------------------------------------------------------------------
extern "C" void kernel_launch(void* const* d_in, const int* in_sizes, int n_in,
                              void* d_out, int out_size, void* d_ws, size_t ws_size,
                              hipStream_t stream)
{
    // dict order: inputs, ref, w1, w2, gamma (dead conv on `inputs` skipped)
    const float* ref = (const float*)d_in[1];
    const float* w1  = (const float*)d_in[2];
    const float* w2  = (const float*)d_in[3];
    const float* gma = (const float*)d_in[4];
    float* out = (float*)d_out;

    u16* padded = (u16*)d_ws;                                  // [B][4356][256] bf16
    u16* wk1 = padded + (size_t)4 * PPIX * CDIM;               // [9][256][256] bf16
    u16* wk2 = wk1 + (size_t)9 * 65536;
    u16* XT  = wk2 + (size_t)9 * 65536;                        // [B][N][C] bf16 (Q=K)
    u16* Vn  = XT + (size_t)4 * NSEQ * CDIM;                   // [B][C][N] bf16 (V)

    hipMemsetAsync(padded, 0, (size_t)4 * PPIX * CDIM * sizeof(u16), stream);
    pad_transpose_kernel<<<dim3(64, 4, 4), 256, 0, stream>>>(ref, padded);
    w_prepack_kernel<<<dim3(256), 256, 0, stream>>>(w1, wk1);
    w_prepack_kernel<<<dim3(256), 256, 0, stream>>>(w2, wk2);

    dim3 cgrid(2, 64, 4);
    conv_mfma_kernel<false><<<cgrid, 256, 0, stream>>>(padded, wk1, XT);  // -> XT
    conv_mfma_kernel<true ><<<cgrid, 256, 0, stream>>>(padded, wk2, Vn);  // -> Vn

    attn_mfma_kernel<<<dim3(4, NSEQ / M_TILE), 256, 0, stream>>>(XT, Vn, ref, gma, out);
}

// Round 5
// 214.038 us; speedup vs baseline: 19.2693x; 1.2920x over previous
//
#include <hip/hip_runtime.h>
#include <math.h>

#define CDIM 256
#define NSEQ 4096
#define HWDIM 64
#define PPIX 4356   // 66*66 padded pixels

typedef unsigned short u16;
typedef __attribute__((ext_vector_type(8))) short bf16x8;
typedef __attribute__((ext_vector_type(4))) float f32x4;

__device__ __forceinline__ u16 f2bf(float f) {
    unsigned u = __float_as_uint(f);
    unsigned r = (u + 0x7FFFu + ((u >> 16) & 1u)) >> 16;   // RN-even
    return (u16)r;
}

// async global->LDS, 16B per lane; LDS dest = wave-uniform base + lane*16
__device__ __forceinline__ void gload_lds16(const u16* g, u16* l) {
    __builtin_amdgcn_global_load_lds(
        (const __attribute__((address_space(1))) unsigned int*)g,
        (__attribute__((address_space(3))) unsigned int*)l, 16, 0, 0);
}

// ---------------------------------------------------------------------------
// pad+transpose: ref fp32 NCHW -> padded bf16 [b][pp][c], pp=(y+1)*66+(x+1)
// ---------------------------------------------------------------------------
__global__ __launch_bounds__(256)
void pad_transpose_kernel(const float* __restrict__ x, u16* __restrict__ padded)
{
    __shared__ float lds[64 * 65];
    const int tid = threadIdx.x;
    const int y = blockIdx.x, c0 = blockIdx.y << 6, b = blockIdx.z;
    #pragma unroll
    for (int i = 0; i < 16; ++i) {
        int f = tid + (i << 8);
        int c = f >> 6, xx = f & 63;
        lds[c * 65 + xx] = x[(((size_t)(b * CDIM + c0 + c)) * HWDIM + y) * HWDIM + xx];
    }
    __syncthreads();
    #pragma unroll
    for (int i = 0; i < 2; ++i) {
        int f = tid + (i << 8);
        int xx = f >> 3, c8 = f & 7;
        union { u16 h[8]; float4 v; } pk;
        #pragma unroll
        for (int j = 0; j < 8; ++j) pk.h[j] = f2bf(lds[(c8 * 8 + j) * 65 + xx]);
        *(float4*)&padded[((size_t)b * PPIX + (y + 1) * 66 + (xx + 1)) * CDIM + c0 + (c8 << 3)] = pk.v;
    }
}

// ---------------------------------------------------------------------------
// weight prepack: w fp32 [co][ci][3][3] -> wk bf16 [kyx][co][ci]
// ---------------------------------------------------------------------------
__global__ __launch_bounds__(256)
void w_prepack_kernel(const float* __restrict__ w, u16* __restrict__ wk)
{
    int t = (blockIdx.x << 8) + threadIdx.x;
    const float* wp = w + (size_t)t * 9;
    #pragma unroll
    for (int j = 0; j < 9; ++j) wk[j * 65536 + t] = f2bf(wp[j]);
}

// ---------------------------------------------------------------------------
// conv3x3+ReLU as 9 offset-GEMMs over the padded image. bf16 MFMA, fp32 acc.
// OA=true : D[n][co] -> Vn[b][co][n]   (conv2)
// OA=false: D[co][n] -> XT[b][n][co]   (conv1)
// ---------------------------------------------------------------------------
template <bool OA>
__global__ __launch_bounds__(256)
void conv_mfma_kernel(const u16* __restrict__ padded, const u16* __restrict__ wk,
                      u16* __restrict__ out)
{
    __shared__ alignas(16) u16 Xs[64 * 64];
    __shared__ alignas(16) u16 Ws[128 * 64];

    const int tid = threadIdx.x;
    const int lane = tid & 63, wv = tid >> 6;
    const int lr = lane & 15, lg = lane >> 4;
    const int cb = blockIdx.x << 7;
    const int y0 = blockIdx.y;
    const int b = blockIdx.z;

    constexpr int MF = OA ? 4 : 2;
    constexpr int NF = OA ? 2 : 4;
    f32x4 acc[MF][NF] = {};

    for (int t = 0; t < 36; ++t) {
        const int kyx = t >> 2, cib = (t & 3) << 6;
        const int ky = kyx / 3, kx = kyx - ky * 3;
        __syncthreads();
        #pragma unroll
        for (int i = 0; i < 2; ++i) {
            int f = tid + (i << 8);
            int r = f >> 3, c8 = f & 7;
            int pp = (y0 + ky) * 66 + r + kx;
            float4 v = *(const float4*)&padded[((size_t)b * PPIX + pp) * CDIM + cib + (c8 << 3)];
            *(float4*)&Xs[(r << 6) + ((c8 << 3) ^ ((r & 7) << 3))] = v;
        }
        #pragma unroll
        for (int i = 0; i < 4; ++i) {
            int f = tid + (i << 8);
            int r = f >> 3, c8 = f & 7;
            float4 v = *(const float4*)&wk[((size_t)kyx << 16) + (size_t)(cb + r) * 256 + cib + (c8 << 3)];
            *(float4*)&Ws[(r << 6) + ((c8 << 3) ^ ((r & 7) << 3))] = v;
        }
        __syncthreads();
        #pragma unroll
        for (int kk = 0; kk < 2; ++kk) {
            const int ca = ((kk << 5) + (lg << 3)) ^ ((lr & 7) << 3);
            if constexpr (OA) {
                bf16x8 a[4], bb[2];
                #pragma unroll
                for (int mf = 0; mf < 4; ++mf)
                    a[mf] = *(const bf16x8*)&Xs[((mf * 16 + lr) << 6) + ca];
                #pragma unroll
                for (int nf = 0; nf < 2; ++nf)
                    bb[nf] = *(const bf16x8*)&Ws[((wv * 32 + nf * 16 + lr) << 6) + ca];
                #pragma unroll
                for (int mf = 0; mf < 4; ++mf)
                    #pragma unroll
                    for (int nf = 0; nf < 2; ++nf)
                        acc[mf][nf] = __builtin_amdgcn_mfma_f32_16x16x32_bf16(a[mf], bb[nf], acc[mf][nf], 0, 0, 0);
            } else {
                bf16x8 a[2], bb[4];
                #pragma unroll
                for (int mf = 0; mf < 2; ++mf)
                    a[mf] = *(const bf16x8*)&Ws[((wv * 32 + mf * 16 + lr) << 6) + ca];
                #pragma unroll
                for (int nf = 0; nf < 4; ++nf)
                    bb[nf] = *(const bf16x8*)&Xs[((nf * 16 + lr) << 6) + ca];
                #pragma unroll
                for (int mf = 0; mf < 2; ++mf)
                    #pragma unroll
                    for (int nf = 0; nf < 4; ++nf)
                        acc[mf][nf] = __builtin_amdgcn_mfma_f32_16x16x32_bf16(a[mf], bb[nf], acc[mf][nf], 0, 0, 0);
            }
        }
    }

    const int m0 = y0 << 6;
    if constexpr (OA) {
        #pragma unroll
        for (int mf = 0; mf < 4; ++mf)
            #pragma unroll
            for (int nf = 0; nf < 2; ++nf) {
                int nb = m0 + mf * 16 + lg * 4;
                int co = cb + wv * 32 + nf * 16 + lr;
                union { u16 h[4]; uint2 v; } pk;
                #pragma unroll
                for (int j = 0; j < 4; ++j) pk.h[j] = f2bf(fmaxf(acc[mf][nf][j], 0.f));
                *(uint2*)&out[((size_t)(b * CDIM + co)) * NSEQ + nb] = pk.v;
            }
    } else {
        #pragma unroll
        for (int mf = 0; mf < 2; ++mf)
            #pragma unroll
            for (int nf = 0; nf < 4; ++nf) {
                int cob = cb + wv * 32 + mf * 16 + lg * 4;
                int n = m0 + nf * 16 + lr;
                union { u16 h[4]; uint2 v; } pk;
                #pragma unroll
                for (int j = 0; j < 4; ++j) pk.h[j] = f2bf(fmaxf(acc[mf][nf][j], 0.f));
                *(uint2*)&out[((size_t)(b * NSEQ + n)) * CDIM + cob] = pk.v;
            }
    }
}

// ---------------------------------------------------------------------------
// Flash attention partials with 2-way key split.
// 512 thr (8 waves x 16 rows = M_TILE 128). Block (b,h,tile) processes keys
// [h*2048, h*2048+2048) in 32 chunks of 64, double-buffered global_load_lds.
// h=0: unnormalized O fp32 -> o0 (=d_out). h=1: O bf16 -> o1 (ws).
// (m,l) per row per half -> ml ws. Merge kernel combines.
// ---------------------------------------------------------------------------
#define M_TILE 128
#define NC 64
#define NCHUNKS 32

// stage one K/V chunk (keys n0..n0+63); 8 gloads per wave (512 thr total)
__device__ __forceinline__ void stage_chunk(const u16* __restrict__ XT, const u16* __restrict__ Vn,
                                            u16* Kb, u16* Vb, int b, int n0, int wv, int lane)
{
    #pragma unroll
    for (int i = 0; i < 4; ++i) {
        int f = ((i << 3) + wv) << 6;          // wave-uniform 16B-unit base
        int fl = f + lane;
        int r = fl >> 5;                        // key row 0..63
        int gsw = (fl & 31) ^ (r & 7);          // pre-swizzled source group
        gload_lds16(&XT[(size_t)(b * NSEQ + n0 + r) * CDIM + (gsw << 3)], Kb + (f << 3));
    }
    #pragma unroll
    for (int i = 0; i < 4; ++i) {
        int f = ((i << 3) + wv) << 6;
        int fl = f + lane;
        int r = fl >> 3;                        // channel row 0..255
        int gsw = (fl & 7) ^ (r & 7);
        gload_lds16(&Vn[(size_t)(b * CDIM + r) * NSEQ + n0 + (gsw << 3)], Vb + (f << 3));
    }
}

__global__ __launch_bounds__(512)
void attn_part_kernel(const u16* __restrict__ XT, const u16* __restrict__ Vn,
                      float* __restrict__ o0, u16* __restrict__ o1,
                      float* __restrict__ ml)
{
    __shared__ alignas(16) u16 smem[73728];     // 144 KB
    // [Ks0 16384][Ks1 16384][Vs0 16384][Vs1 16384][Ps 8192]
    u16* Ps = smem + 65536;

    const int tid = threadIdx.x;
    const int lane = tid & 63;
    const int wv = tid >> 6;                    // 0..7
    const int lr = lane & 15;
    const int lg = lane >> 4;
    const int bh = blockIdx.x;                  // b*2+h -> XCD affinity per key-half
    const int b = bh >> 1, h = bh & 1;
    const int m0 = blockIdx.y * M_TILE;
    const int nbase = h * (NSEQ / 2);

    // Q in registers: lane holds A-frags for row m0 + wv*16 + lr
    bf16x8 qreg[8];
    {
        const u16* qrow = &XT[(size_t)(b * NSEQ + m0 + wv * 16 + lr) * CDIM + (lg << 3)];
        #pragma unroll
        for (int kk = 0; kk < 8; ++kk)
            qreg[kk] = *(const bf16x8*)(qrow + (kk << 5));
    }

    f32x4 o[16] = {};
    float mrun[4] = {-INFINITY, -INFINITY, -INFINITY, -INFINITY};
    float lrun[4] = {0.f, 0.f, 0.f, 0.f};

    stage_chunk(XT, Vn, smem, smem + 32768, b, nbase, wv, lane);
    __syncthreads();

    int cur = 0;
    for (int ci = 0; ci < NCHUNKS; ++ci) {
        if (ci + 1 < NCHUNKS)
            stage_chunk(XT, Vn, smem + (cur ^ 1) * 16384, smem + 32768 + (cur ^ 1) * 16384,
                        b, nbase + (ci + 1) * NC, wv, lane);

        const u16* Kc = smem + cur * 16384;
        const u16* Vc = smem + 32768 + cur * 16384;

        // ---- QK^T ----
        f32x4 s[4] = {};
        #pragma unroll
        for (int kk = 0; kk < 8; ++kk) {
            const int ca = ((kk << 5) + (lg << 3)) ^ ((lr & 7) << 3);
            #pragma unroll
            for (int t = 0; t < 4; ++t) {
                bf16x8 kb = *(const bf16x8*)&Kc[(t * 16 + lr) * 256 + ca];
                s[t] = __builtin_amdgcn_mfma_f32_16x16x32_bf16(qreg[kk], kb, s[t], 0, 0, 0);
            }
        }

        // ---- online softmax ----
        #pragma unroll
        for (int r = 0; r < 4; ++r) {
            float v0 = s[0][r], v1 = s[1][r], v2 = s[2][r], v3 = s[3][r];
            float cm = fmaxf(fmaxf(v0, v1), fmaxf(v2, v3));
            cm = fmaxf(cm, __shfl_xor(cm, 1));
            cm = fmaxf(cm, __shfl_xor(cm, 2));
            cm = fmaxf(cm, __shfl_xor(cm, 4));
            cm = fmaxf(cm, __shfl_xor(cm, 8));
            float mnew = fmaxf(mrun[r], cm);
            float al = __expf(mrun[r] - mnew);
            float p0 = __expf(v0 - mnew), p1 = __expf(v1 - mnew);
            float p2 = __expf(v2 - mnew), p3 = __expf(v3 - mnew);
            float sm = p0 + p1 + p2 + p3;
            sm += __shfl_xor(sm, 1);
            sm += __shfl_xor(sm, 2);
            sm += __shfl_xor(sm, 4);
            sm += __shfl_xor(sm, 8);
            lrun[r] = lrun[r] * al + sm;
            mrun[r] = mnew;
            const int mrow = wv * 16 + lg * 4 + r;
            const int swz = (mrow & 7) << 3;
            Ps[mrow * 64 + ((     lr) ^ swz)] = f2bf(p0);
            Ps[mrow * 64 + ((16 + lr) ^ swz)] = f2bf(p1);
            Ps[mrow * 64 + ((32 + lr) ^ swz)] = f2bf(p2);
            Ps[mrow * 64 + ((48 + lr) ^ swz)] = f2bf(p3);
            #pragma unroll
            for (int cs = 0; cs < 16; ++cs) o[cs][r] *= al;
        }

        // ---- PV (wave-local P round-trip; same-wave DS ops in-order) ----
        #pragma unroll
        for (int ks = 0; ks < 2; ++ks) {
            const int ca = ((ks << 5) + (lg << 3)) ^ ((lr & 7) << 3);
            bf16x8 pa = *(const bf16x8*)&Ps[(wv * 16 + lr) * 64 + ca];
            #pragma unroll
            for (int cs = 0; cs < 16; ++cs) {
                bf16x8 vb = *(const bf16x8*)&Vc[(cs * 16 + lr) * 64 + ca];
                o[cs] = __builtin_amdgcn_mfma_f32_16x16x32_bf16(pa, vb, o[cs], 0, 0, 0);
            }
        }

        __syncthreads();
        cur ^= 1;
    }

    // ---- write (m,l) per row ----
    if (lr == 0) {
        #pragma unroll
        for (int r = 0; r < 4; ++r) {
            const int mrow = wv * 16 + lg * 4 + r;
            size_t idx = ((size_t)((h * 4 + b) * NSEQ) + m0 + mrow) * 2;
            ml[idx] = mrun[r];
            ml[idx + 1] = lrun[r];
        }
    }

    // ---- epilogue: LDS transpose (unnormalized), coalesced [c][n] partial out ----
    float* olds = (float*)smem;            // [128][257] f32 overlay (131.6 KB)
    #pragma unroll
    for (int r = 0; r < 4; ++r) {
        const int mrow = wv * 16 + lg * 4 + r;
        #pragma unroll
        for (int cs = 0; cs < 16; ++cs)
            olds[mrow * 257 + cs * 16 + lr] = o[cs][r];
    }
    __syncthreads();
    if (h == 0) {
        #pragma unroll 8
        for (int i = 0; i < 64; ++i) {
            int f = tid + (i << 9);
            int c = f >> 7, mm_ = f & 127;
            o0[((size_t)(b * CDIM + c)) * NSEQ + m0 + mm_] = olds[mm_ * 257 + c];
        }
    } else {
        #pragma unroll 8
        for (int i = 0; i < 64; ++i) {
            int f = tid + (i << 9);
            int c = f >> 7, mm_ = f & 127;
            o1[((size_t)(b * CDIM + c)) * NSEQ + m0 + mm_] = f2bf(olds[mm_ * 257 + c]);
        }
    }
}

// ---------------------------------------------------------------------------
// merge: out[i] = g * (O0[i]*w0 + O1[i]*w1) / l + ref[i]   (in-place on d_out,
// element-wise: same thread reads o0[i] and writes out[i] -> race-free)
// ---------------------------------------------------------------------------
__global__ __launch_bounds__(256)
void merge_kernel(float* __restrict__ out, const u16* __restrict__ o1,
                  const float* __restrict__ ml, const float* __restrict__ ref,
                  const float* __restrict__ gptr)
{
    const int f = (blockIdx.x << 8) + threadIdx.x;   // per float4 of out
    const int n4 = f & 1023;                          // n0 = n4*4
    const int c = (f >> 10) & 255;
    const int b = f >> 18;
    const float g = gptr[0];

    float4 p0 = ((const float4*)out)[f];
    uint2 q1 = *(const uint2*)&o1[((size_t)(b * CDIM + c)) * NSEQ + (n4 << 2)];
    float4 rf = ((const float4*)ref)[f];

    float res[4];
    #pragma unroll
    for (int j = 0; j < 4; ++j) {
        int row = (n4 << 2) + j;
        size_t i0 = ((size_t)(0 + b) * NSEQ + row) * 2;
        size_t i1 = ((size_t)(4 + b) * NSEQ + row) * 2;
        float m0 = ml[i0], l0 = ml[i0 + 1];
        float m1 = ml[i1], l1 = ml[i1 + 1];
        float mm = fmaxf(m0, m1);
        float w0 = __expf(m0 - mm), w1 = __expf(m1 - mm);
        float rl = 1.0f / (l0 * w0 + l1 * w1);
        float v0 = ((const float*)&p0)[j];
        float v1 = __uint_as_float((unsigned)((&q1.x)[j >> 1] >> ((j & 1) * 16) << 16) & 0xFFFF0000u);
        // note: extract u16 then <<16
        unsigned hu = ((j & 1) ? ((&q1.x)[j >> 1] >> 16) : ((&q1.x)[j >> 1] & 0xFFFFu));
        v1 = __uint_as_float(hu << 16);
        float a = (v0 * w0 + v1 * w1) * rl;
        res[j] = g * a + ((const float*)&rf)[j];
    }
    ((float4*)out)[f] = *(float4*)res;
}

// ---------------------------------------------------------------------------
extern "C" void kernel_launch(void* const* d_in, const int* in_sizes, int n_in,
                              void* d_out, int out_size, void* d_ws, size_t ws_size,
                              hipStream_t stream)
{
    // dict order: inputs, ref, w1, w2, gamma (dead conv on `inputs` skipped)
    const float* ref = (const float*)d_in[1];
    const float* w1  = (const float*)d_in[2];
    const float* w2  = (const float*)d_in[3];
    const float* gma = (const float*)d_in[4];
    float* out = (float*)d_out;

    u16* XT     = (u16*)d_ws;                          // [B][N][C] bf16 (Q=K)  8.39 MB
    u16* Vn     = XT + (size_t)4 * NSEQ * CDIM;        // [B][C][N] bf16 (V)    8.39 MB
    u16* padded = Vn + (size_t)4 * NSEQ * CDIM;        // [B][4356][256] bf16   8.9 MB (dead after convs)
    u16* wk1    = padded + (size_t)4 * PPIX * CDIM;    // 1.18 MB (dead after convs)
    u16* wk2    = wk1 + (size_t)9 * 65536;             // 1.18 MB (dead after convs)
    // attn-phase reuse of dead regions:
    u16*   o1  = padded;                               // [B][C][N] bf16 partial (8.39 MB <= padded)
    float* ml  = (float*)wk1;                          // [2][B][N][2] f32 (0.26 MB <= wk)

    hipMemsetAsync(padded, 0, (size_t)4 * PPIX * CDIM * sizeof(u16), stream);
    pad_transpose_kernel<<<dim3(64, 4, 4), 256, 0, stream>>>(ref, padded);
    w_prepack_kernel<<<dim3(256), 256, 0, stream>>>(w1, wk1);
    w_prepack_kernel<<<dim3(256), 256, 0, stream>>>(w2, wk2);

    dim3 cgrid(2, 64, 4);
    conv_mfma_kernel<false><<<cgrid, 256, 0, stream>>>(padded, wk1, XT);  // -> XT
    conv_mfma_kernel<true ><<<cgrid, 256, 0, stream>>>(padded, wk2, Vn);  // -> Vn

    attn_part_kernel<<<dim3(8, NSEQ / M_TILE), 512, 0, stream>>>(XT, Vn, out, o1, ml);
    merge_kernel<<<dim3((4 * CDIM * NSEQ / 4) / 256), 256, 0, stream>>>(out, o1, ml, ref, gma);
}

// Round 6
// 189.412 us; speedup vs baseline: 21.7745x; 1.1300x over previous
//
#include <hip/hip_runtime.h>
#include <math.h>

#define CDIM 256
#define NSEQ 4096
#define HWDIM 64
#define PPIX 4356   // 66*66 padded pixels

typedef unsigned short u16;
typedef __attribute__((ext_vector_type(8))) short bf16x8;
typedef __attribute__((ext_vector_type(4))) float f32x4;

__device__ __forceinline__ u16 f2bf(float f) {
    unsigned u = __float_as_uint(f);
    unsigned r = (u + 0x7FFFu + ((u >> 16) & 1u)) >> 16;   // RN-even
    return (u16)r;
}

// async global->LDS, 16B per lane; LDS dest = wave-uniform base + lane*16
__device__ __forceinline__ void gload_lds16(const u16* g, u16* l) {
    __builtin_amdgcn_global_load_lds(
        (const __attribute__((address_space(1))) unsigned int*)g,
        (__attribute__((address_space(3))) unsigned int*)l, 16, 0, 0);
}

// ---------------------------------------------------------------------------
// pad+transpose: ref fp32 NCHW -> padded bf16 [b][pp][c], pp=(y+1)*66+(x+1)
// ---------------------------------------------------------------------------
__global__ __launch_bounds__(256)
void pad_transpose_kernel(const float* __restrict__ x, u16* __restrict__ padded)
{
    __shared__ float lds[64 * 65];
    const int tid = threadIdx.x;
    const int y = blockIdx.x, c0 = blockIdx.y << 6, b = blockIdx.z;
    #pragma unroll
    for (int i = 0; i < 16; ++i) {
        int f = tid + (i << 8);
        int c = f >> 6, xx = f & 63;
        lds[c * 65 + xx] = x[(((size_t)(b * CDIM + c0 + c)) * HWDIM + y) * HWDIM + xx];
    }
    __syncthreads();
    #pragma unroll
    for (int i = 0; i < 2; ++i) {
        int f = tid + (i << 8);
        int xx = f >> 3, c8 = f & 7;
        union { u16 h[8]; float4 v; } pk;
        #pragma unroll
        for (int j = 0; j < 8; ++j) pk.h[j] = f2bf(lds[(c8 * 8 + j) * 65 + xx]);
        *(float4*)&padded[((size_t)b * PPIX + (y + 1) * 66 + (xx + 1)) * CDIM + c0 + (c8 << 3)] = pk.v;
    }
}

// ---------------------------------------------------------------------------
// weight prepack: w fp32 [co][ci][3][3] -> wk bf16 [kyx][co][ci]
// ---------------------------------------------------------------------------
__global__ __launch_bounds__(256)
void w_prepack_kernel(const float* __restrict__ w, u16* __restrict__ wk)
{
    int t = (blockIdx.x << 8) + threadIdx.x;
    const float* wp = w + (size_t)t * 9;
    #pragma unroll
    for (int j = 0; j < 9; ++j) wk[j * 65536 + t] = f2bf(wp[j]);
}

// ---------------------------------------------------------------------------
// conv3x3+ReLU as 9 offset-GEMMs over the padded image. bf16 MFMA, fp32 acc.
// OA=true : D[n][co] -> Vn[b][co][n]   (conv2)
// OA=false: D[co][n] -> XT[b][n][co]   (conv1)
// ---------------------------------------------------------------------------
template <bool OA>
__global__ __launch_bounds__(256)
void conv_mfma_kernel(const u16* __restrict__ padded, const u16* __restrict__ wk,
                      u16* __restrict__ out)
{
    __shared__ alignas(16) u16 Xs[64 * 64];
    __shared__ alignas(16) u16 Ws[128 * 64];

    const int tid = threadIdx.x;
    const int lane = tid & 63, wv = tid >> 6;
    const int lr = lane & 15, lg = lane >> 4;
    const int cb = blockIdx.x << 7;
    const int y0 = blockIdx.y;
    const int b = blockIdx.z;

    constexpr int MF = OA ? 4 : 2;
    constexpr int NF = OA ? 2 : 4;
    f32x4 acc[MF][NF] = {};

    for (int t = 0; t < 36; ++t) {
        const int kyx = t >> 2, cib = (t & 3) << 6;
        const int ky = kyx / 3, kx = kyx - ky * 3;
        __syncthreads();
        #pragma unroll
        for (int i = 0; i < 2; ++i) {
            int f = tid + (i << 8);
            int r = f >> 3, c8 = f & 7;
            int pp = (y0 + ky) * 66 + r + kx;
            float4 v = *(const float4*)&padded[((size_t)b * PPIX + pp) * CDIM + cib + (c8 << 3)];
            *(float4*)&Xs[(r << 6) + ((c8 << 3) ^ ((r & 7) << 3))] = v;
        }
        #pragma unroll
        for (int i = 0; i < 4; ++i) {
            int f = tid + (i << 8);
            int r = f >> 3, c8 = f & 7;
            float4 v = *(const float4*)&wk[((size_t)kyx << 16) + (size_t)(cb + r) * 256 + cib + (c8 << 3)];
            *(float4*)&Ws[(r << 6) + ((c8 << 3) ^ ((r & 7) << 3))] = v;
        }
        __syncthreads();
        #pragma unroll
        for (int kk = 0; kk < 2; ++kk) {
            const int ca = ((kk << 5) + (lg << 3)) ^ ((lr & 7) << 3);
            if constexpr (OA) {
                bf16x8 a[4], bb[2];
                #pragma unroll
                for (int mf = 0; mf < 4; ++mf)
                    a[mf] = *(const bf16x8*)&Xs[((mf * 16 + lr) << 6) + ca];
                #pragma unroll
                for (int nf = 0; nf < 2; ++nf)
                    bb[nf] = *(const bf16x8*)&Ws[((wv * 32 + nf * 16 + lr) << 6) + ca];
                #pragma unroll
                for (int mf = 0; mf < 4; ++mf)
                    #pragma unroll
                    for (int nf = 0; nf < 2; ++nf)
                        acc[mf][nf] = __builtin_amdgcn_mfma_f32_16x16x32_bf16(a[mf], bb[nf], acc[mf][nf], 0, 0, 0);
            } else {
                bf16x8 a[2], bb[4];
                #pragma unroll
                for (int mf = 0; mf < 2; ++mf)
                    a[mf] = *(const bf16x8*)&Ws[((wv * 32 + mf * 16 + lr) << 6) + ca];
                #pragma unroll
                for (int nf = 0; nf < 4; ++nf)
                    bb[nf] = *(const bf16x8*)&Xs[((nf * 16 + lr) << 6) + ca];
                #pragma unroll
                for (int mf = 0; mf < 2; ++mf)
                    #pragma unroll
                    for (int nf = 0; nf < 4; ++nf)
                        acc[mf][nf] = __builtin_amdgcn_mfma_f32_16x16x32_bf16(a[mf], bb[nf], acc[mf][nf], 0, 0, 0);
            }
        }
    }

    const int m0 = y0 << 6;
    if constexpr (OA) {
        #pragma unroll
        for (int mf = 0; mf < 4; ++mf)
            #pragma unroll
            for (int nf = 0; nf < 2; ++nf) {
                int nb = m0 + mf * 16 + lg * 4;
                int co = cb + wv * 32 + nf * 16 + lr;
                union { u16 h[4]; uint2 v; } pk;
                #pragma unroll
                for (int j = 0; j < 4; ++j) pk.h[j] = f2bf(fmaxf(acc[mf][nf][j], 0.f));
                *(uint2*)&out[((size_t)(b * CDIM + co)) * NSEQ + nb] = pk.v;
            }
    } else {
        #pragma unroll
        for (int mf = 0; mf < 2; ++mf)
            #pragma unroll
            for (int nf = 0; nf < 4; ++nf) {
                int cob = cb + wv * 32 + mf * 16 + lg * 4;
                int n = m0 + nf * 16 + lr;
                union { u16 h[4]; uint2 v; } pk;
                #pragma unroll
                for (int j = 0; j < 4; ++j) pk.h[j] = f2bf(fmaxf(acc[mf][nf][j], 0.f));
                *(uint2*)&out[((size_t)(b * NSEQ + n)) * CDIM + cob] = pk.v;
            }
    }
}

// ---------------------------------------------------------------------------
// Flash attention partials, 2-way key split, SWAPPED-operand QK:
//   scores D[key][query] = mfma(K_frag, Q_frag)  -> query is lane-resident
//   softmax: 15-op VALU tree + 2 shfls per chunk (lane-parallel over queries)
//   P -> LDS [q][key] (b64 packed writes), PV c-split: O^T[c][q] = mfma(V,P)
// 512 thr (8 waves). QK: wave owns 16 q. PV: wave owns (q-half, c-half).
// ---------------------------------------------------------------------------
#define M_TILE 128
#define NC 64
#define NCHUNKS 32

// LDS map (u16 units): Ks dbuf 2x16384, Vs dbuf 2x16384, P 8192, al 256
#define KS_OFF 0
#define VS_OFF 32768
#define P_OFF  65536
#define AL_OFF 73728

// stage one K/V chunk (keys n0..n0+63); 8 gloads per wave (512 thr total)
__device__ __forceinline__ void stage_chunk(const u16* __restrict__ XT, const u16* __restrict__ Vn,
                                            u16* Kb, u16* Vb, int b, int n0, int wv, int lane)
{
    #pragma unroll
    for (int i = 0; i < 4; ++i) {
        int f = ((i << 3) + wv) << 6;          // wave-uniform 16B-unit base
        int fl = f + lane;
        int r = fl >> 5;                        // key row 0..63
        int gsw = (fl & 31) ^ (r & 7);          // pre-swizzled source group
        gload_lds16(&XT[(size_t)(b * NSEQ + n0 + r) * CDIM + (gsw << 3)], Kb + (f << 3));
    }
    #pragma unroll
    for (int i = 0; i < 4; ++i) {
        int f = ((i << 3) + wv) << 6;
        int fl = f + lane;
        int r = fl >> 3;                        // channel row 0..255
        int gsw = (fl & 7) ^ (r & 7);
        gload_lds16(&Vn[(size_t)(b * CDIM + r) * NSEQ + n0 + (gsw << 3)], Vb + (f << 3));
    }
}

__global__ __launch_bounds__(512)
void attn_part_kernel(const u16* __restrict__ XT, const u16* __restrict__ Vn,
                      float* __restrict__ o0, u16* __restrict__ o1,
                      float* __restrict__ ml)
{
    __shared__ alignas(16) u16 smem[73984];     // 144.5 KB
    u16* Ps = smem + P_OFF;
    float* al_lds = (float*)(smem + AL_OFF);

    const int tid = threadIdx.x;
    const int lane = tid & 63;
    const int wv = tid >> 6;                    // 0..7
    const int lr = lane & 15;
    const int lg = lane >> 4;
    const int bh = blockIdx.x;                  // b*2+h
    const int b = bh >> 1, h = bh & 1;
    const int m0 = blockIdx.y * M_TILE;
    const int nbase = h * (NSEQ / 2);

    // Q as MFMA B-operand fragments, in registers.
    // B-frag: col(q) = lane&15, k = kk*32 + lg*8 + j
    const int qq = wv * 16 + lr;                // QK-phase query owned by this lane
    bf16x8 qreg[8];
    {
        const u16* qrow = &XT[(size_t)(b * NSEQ + m0 + qq) * CDIM + (lg << 3)];
        #pragma unroll
        for (int kk = 0; kk < 8; ++kk)
            qreg[kk] = *(const bf16x8*)(qrow + (kk << 5));
    }

    // PV ownership: q-half qh (32 q), c-half ch (128 c)
    const int qh = wv & 3, ch = wv >> 2;

    f32x4 o[2][8] = {};                         // [qf][cf] : O^T[c][q] unnormalized
    float mrun = -INFINITY, lrun = 0.f;         // per-lane query state (dup over lg)

    stage_chunk(XT, Vn, smem + KS_OFF, smem + VS_OFF, b, nbase, wv, lane);
    __syncthreads();

    int cur = 0;
    for (int ci = 0; ci < NCHUNKS; ++ci) {
        if (ci + 1 < NCHUNKS)
            stage_chunk(XT, Vn, smem + KS_OFF + (cur ^ 1) * 16384,
                        smem + VS_OFF + (cur ^ 1) * 16384,
                        b, nbase + (ci + 1) * NC, wv, lane);

        const u16* Kc = smem + KS_OFF + cur * 16384;
        const u16* Vc = smem + VS_OFF + cur * 16384;

        // ---- QK^T (swapped): s[kf] = D[key][q], key = kf*16 + lg*4 + r ----
        f32x4 s[4] = {};
        #pragma unroll
        for (int kk = 0; kk < 8; ++kk) {
            const int ca = ((kk << 5) + (lg << 3)) ^ ((lr & 7) << 3);
            #pragma unroll
            for (int kf = 0; kf < 4; ++kf) {
                bf16x8 ka = *(const bf16x8*)&Kc[(kf * 16 + lr) * 256 + ca];
                s[kf] = __builtin_amdgcn_mfma_f32_16x16x32_bf16(ka, qreg[kk], s[kf], 0, 0, 0);
            }
        }

        // ---- softmax: lane-parallel over queries ----
        float cmax = fmaxf(fmaxf(fmaxf(s[0][0], s[0][1]), fmaxf(s[0][2], s[0][3])),
                           fmaxf(fmaxf(s[1][0], s[1][1]), fmaxf(s[1][2], s[1][3])));
        cmax = fmaxf(cmax,
               fmaxf(fmaxf(fmaxf(s[2][0], s[2][1]), fmaxf(s[2][2], s[2][3])),
                     fmaxf(fmaxf(s[3][0], s[3][1]), fmaxf(s[3][2], s[3][3]))));
        cmax = fmaxf(cmax, __shfl_xor(cmax, 16));
        cmax = fmaxf(cmax, __shfl_xor(cmax, 32));
        float mnew = fmaxf(mrun, cmax);
        float al = __expf(mrun - mnew);
        float p[4][4];
        float psum = 0.f;
        #pragma unroll
        for (int kf = 0; kf < 4; ++kf) {
            #pragma unroll
            for (int r = 0; r < 4; ++r) {
                p[kf][r] = __expf(s[kf][r] - mnew);
                psum += p[kf][r];
            }
        }
        psum += __shfl_xor(psum, 16);
        psum += __shfl_xor(psum, 32);
        lrun = lrun * al + psum;
        mrun = mnew;

        // ---- P -> LDS [q][key^swz], packed 4 keys per b64 write ----
        {
            const int swz = (qq & 7) << 3;
            #pragma unroll
            for (int kf = 0; kf < 4; ++kf) {
                union { u16 h4[4]; uint2 v; } pk;
                pk.h4[0] = f2bf(p[kf][0]); pk.h4[1] = f2bf(p[kf][1]);
                pk.h4[2] = f2bf(p[kf][2]); pk.h4[3] = f2bf(p[kf][3]);
                *(uint2*)&Ps[qq * 64 + (((kf << 4) + (lg << 2)) ^ swz)] = pk.v;
            }
            if (lg == 0) al_lds[qq] = al;
        }
        __syncthreads();    // barrier A: P + al visible; staging drained

        // ---- PV: O^T[c][q] += V^T[c][n] P[n][q], c-split across waves ----
        float alq0 = al_lds[qh * 32 + lr];
        float alq1 = al_lds[qh * 32 + 16 + lr];
        #pragma unroll
        for (int cf = 0; cf < 8; ++cf) {
            #pragma unroll
            for (int r = 0; r < 4; ++r) { o[0][cf][r] *= alq0; o[1][cf][r] *= alq1; }
        }
        #pragma unroll
        for (int ks = 0; ks < 2; ++ks) {
            bf16x8 va[8];
            #pragma unroll
            for (int cf = 0; cf < 8; ++cf) {
                const int crow = ch * 128 + cf * 16 + lr;
                va[cf] = *(const bf16x8*)&Vc[crow * 64 + (((ks << 5) + (lg << 3)) ^ ((crow & 7) << 3))];
            }
            #pragma unroll
            for (int qf = 0; qf < 2; ++qf) {
                const int qrow = qh * 32 + qf * 16 + lr;
                bf16x8 pb = *(const bf16x8*)&Ps[qrow * 64 + (((ks << 5) + (lg << 3)) ^ ((qrow & 7) << 3))];
                #pragma unroll
                for (int cf = 0; cf < 8; ++cf)
                    o[qf][cf] = __builtin_amdgcn_mfma_f32_16x16x32_bf16(va[cf], pb, o[qf][cf], 0, 0, 0);
            }
        }

        __syncthreads();    // barrier B: PV reads done -> buffers reusable
        cur ^= 1;
    }

    // ---- (m,l) per query (QK-lane layout; lanes with lg==0) ----
    if (lane < 16) {
        size_t idx = ((size_t)((h * 4 + b) * NSEQ) + m0 + qq) * 2;
        ml[idx] = mrun;
        ml[idx + 1] = lrun;
    }

    // ---- partial store: D[c][q] frags map directly to [b][c][m] layout ----
    #pragma unroll
    for (int qf = 0; qf < 2; ++qf) {
        #pragma unroll
        for (int cf = 0; cf < 8; ++cf) {
            #pragma unroll
            for (int r = 0; r < 4; ++r) {
                int c = ch * 128 + cf * 16 + lg * 4 + r;
                int q = m0 + qh * 32 + qf * 16 + lr;
                size_t oi = ((size_t)(b * CDIM + c)) * NSEQ + q;
                if (h == 0) o0[oi] = o[qf][cf][r];
                else        o1[oi] = f2bf(o[qf][cf][r]);
            }
        }
    }
}

// ---------------------------------------------------------------------------
// merge: out[i] = g * (O0[i]*w0 + O1[i]*w1) / l + ref[i]   (in-place on d_out,
// element-wise: same thread reads o0[i] and writes out[i] -> race-free)
// ---------------------------------------------------------------------------
__global__ __launch_bounds__(256)
void merge_kernel(float* __restrict__ out, const u16* __restrict__ o1,
                  const float* __restrict__ ml, const float* __restrict__ ref,
                  const float* __restrict__ gptr)
{
    const int f = (blockIdx.x << 8) + threadIdx.x;   // per float4 of out
    const int n4 = f & 1023;                          // n0 = n4*4
    const int c = (f >> 10) & 255;
    const int b = f >> 18;
    const float g = gptr[0];

    float4 p0 = ((const float4*)out)[f];
    uint2 q1 = *(const uint2*)&o1[((size_t)(b * CDIM + c)) * NSEQ + (n4 << 2)];
    float4 rf = ((const float4*)ref)[f];

    float res[4];
    #pragma unroll
    for (int j = 0; j < 4; ++j) {
        int row = (n4 << 2) + j;
        size_t i0 = ((size_t)(0 + b) * NSEQ + row) * 2;
        size_t i1 = ((size_t)(4 + b) * NSEQ + row) * 2;
        float m0 = ml[i0], l0 = ml[i0 + 1];
        float m1 = ml[i1], l1 = ml[i1 + 1];
        float mm = fmaxf(m0, m1);
        float w0 = __expf(m0 - mm), w1 = __expf(m1 - mm);
        float rl = 1.0f / (l0 * w0 + l1 * w1);
        float v0 = ((const float*)&p0)[j];
        unsigned hu = ((j & 1) ? ((&q1.x)[j >> 1] >> 16) : ((&q1.x)[j >> 1] & 0xFFFFu));
        float v1 = __uint_as_float(hu << 16);
        float a = (v0 * w0 + v1 * w1) * rl;
        res[j] = g * a + ((const float*)&rf)[j];
    }
    ((float4*)out)[f] = *(float4*)res;
}

// ---------------------------------------------------------------------------
extern "C" void kernel_launch(void* const* d_in, const int* in_sizes, int n_in,
                              void* d_out, int out_size, void* d_ws, size_t ws_size,
                              hipStream_t stream)
{
    // dict order: inputs, ref, w1, w2, gamma (dead conv on `inputs` skipped)
    const float* ref = (const float*)d_in[1];
    const float* w1  = (const float*)d_in[2];
    const float* w2  = (const float*)d_in[3];
    const float* gma = (const float*)d_in[4];
    float* out = (float*)d_out;

    u16* XT     = (u16*)d_ws;                          // [B][N][C] bf16 (Q=K)  8.39 MB
    u16* Vn     = XT + (size_t)4 * NSEQ * CDIM;        // [B][C][N] bf16 (V)    8.39 MB
    u16* padded = Vn + (size_t)4 * NSEQ * CDIM;        // [B][4356][256] bf16   8.9 MB (dead after convs)
    u16* wk1    = padded + (size_t)4 * PPIX * CDIM;    // 1.18 MB (dead after convs)
    u16* wk2    = wk1 + (size_t)9 * 65536;             // 1.18 MB (dead after convs)
    // attn-phase reuse of dead regions:
    u16*   o1  = padded;                               // [B][C][N] bf16 partial (8.39 MB <= padded)
    float* ml  = (float*)wk1;                          // [2][B][N][2] f32 (0.26 MB <= wk)

    hipMemsetAsync(padded, 0, (size_t)4 * PPIX * CDIM * sizeof(u16), stream);
    pad_transpose_kernel<<<dim3(64, 4, 4), 256, 0, stream>>>(ref, padded);
    w_prepack_kernel<<<dim3(256), 256, 0, stream>>>(w1, wk1);
    w_prepack_kernel<<<dim3(256), 256, 0, stream>>>(w2, wk2);

    dim3 cgrid(2, 64, 4);
    conv_mfma_kernel<false><<<cgrid, 256, 0, stream>>>(padded, wk1, XT);  // -> XT
    conv_mfma_kernel<true ><<<cgrid, 256, 0, stream>>>(padded, wk2, Vn);  // -> Vn

    attn_part_kernel<<<dim3(8, NSEQ / M_TILE), 512, 0, stream>>>(XT, Vn, out, o1, ml);
    merge_kernel<<<dim3((4 * CDIM * NSEQ / 4) / 256), 256, 0, stream>>>(out, o1, ml, ref, gma);
}